// Round 3
// baseline (965.234 us; speedup 1.0000x reference)
//
#include <hip/hip_runtime.h>

typedef _Float16 f16;
typedef _Float16 f16x4 __attribute__((ext_vector_type(4)));
typedef _Float16 f16x8 __attribute__((ext_vector_type(8)));
typedef float    f32x4 __attribute__((ext_vector_type(4)));

#define AS1 __attribute__((address_space(1)))
#define AS3 __attribute__((address_space(3)))

__device__ __forceinline__ void gl_lds16(const void* g, void* l) {
  __builtin_amdgcn_global_load_lds((const AS1 void*)g, (AS3 void*)l, 16, 0, 0);
}

#define VMCNT0 asm volatile("s_waitcnt vmcnt(0)" ::: "memory")
#define VMCNT2 asm volatile("s_waitcnt vmcnt(2)" ::: "memory")
#define VMCNT4 asm volatile("s_waitcnt vmcnt(4)" ::: "memory")
#define VMCNT6 asm volatile("s_waitcnt vmcnt(6)" ::: "memory")
#define LGKM0  asm volatile("s_waitcnt lgkmcnt(0)" ::: "memory")
#define BAR()  __builtin_amdgcn_s_barrier()

// ===========================================================================
// 128x128 split kernel — retained ONLY for MT (= Wk.Wq^T, 512 blocks).
// ===========================================================================
template <int CMODE>
__global__ __launch_bounds__(256) void gemm_nt3(
    const f16* __restrict__ Ah, const f16* __restrict__ Al,
    const f16* __restrict__ Bh, const f16* __restrict__ Bl,
    void* __restrict__ C, f16* __restrict__ Cl,
    int K, int ldc, int ZB,
    long sA1, long sA2, long sB1, long sB2, long sC1, long sC2, float scale)
{
  __shared__ __align__(16) f16 Ash[128 * 32];
  __shared__ __align__(16) f16 Asl[128 * 32];
  __shared__ __align__(16) f16 Bsh[128 * 32];
  __shared__ __align__(16) f16 Bsl[128 * 32];

  const int tid  = threadIdx.x;
  const int wave = tid >> 6;
  const int lane = tid & 63;
  const int quad = lane >> 4;
  const int col  = lane & 15;
  const int wm = (wave & 1) * 64;
  const int wn = (wave >> 1) * 64;

  const int z  = blockIdx.z;
  const int z1 = z % ZB;
  const int z2 = z / ZB;
  const long offA = (long)z1 * sA1 + (long)z2 * sA2;
  const long offB = (long)z1 * sB1 + (long)z2 * sB2;
  const long offC = (long)z1 * sC1 + (long)z2 * sC2;

  const long tile_m = (long)blockIdx.x * 128;
  const long tile_n = (long)blockIdx.y * 128;

  const int rstage = wave * 16 + (lane >> 2);
  const int kq = ((lane & 3) - ((lane >> 3) & 3)) & 3;
  const int kstage = kq * 8;
  const int lstage = (lane & 3) * 8;
  const long aoff = offA + (tile_m + rstage) * (long)K + kstage;
  const long boff = offB + (tile_n + rstage) * (long)K + kstage;
  const f16* pah = Ah + aoff;
  const f16* pal = Al + aoff;
  const f16* pbh = Bh + boff;
  const f16* pbl = Bl + boff;
  const int lds_o = rstage * 32 + lstage;
  const long skip = 64L * K;

  const int sA_sw = (quad + ((col >> 1) & 3)) & 3;

  f32x4 acc[4][4];
#pragma unroll
  for (int i = 0; i < 4; ++i)
#pragma unroll
    for (int j = 0; j < 4; ++j) acc[i][j] = (f32x4){0.f, 0.f, 0.f, 0.f};

  for (int k0 = 0; k0 < K; k0 += 32) {
    gl_lds16(pah, &Ash[lds_o]);
    gl_lds16(pah + skip, &Ash[lds_o + 64 * 32]);
    gl_lds16(pal, &Asl[lds_o]);
    gl_lds16(pal + skip, &Asl[lds_o + 64 * 32]);
    gl_lds16(pbh, &Bsh[lds_o]);
    gl_lds16(pbh + skip, &Bsh[lds_o + 64 * 32]);
    gl_lds16(pbl, &Bsl[lds_o]);
    gl_lds16(pbl + skip, &Bsl[lds_o + 64 * 32]);
    pah += 32; pal += 32; pbh += 32; pbl += 32;
    __syncthreads();

    const f16x8* A8h = (const f16x8*)Ash;
    const f16x8* A8l = (const f16x8*)Asl;
    const f16x8* B8h = (const f16x8*)Bsh;
    const f16x8* B8l = (const f16x8*)Bsl;
    f16x8 ah[4], al[4], bh[4], bl[4];
#pragma unroll
    for (int i = 0; i < 4; ++i) {
      const int idx = (wm + i * 16 + col) * 4 + sA_sw;
      ah[i] = A8h[idx];
      al[i] = A8l[idx];
    }
#pragma unroll
    for (int j = 0; j < 4; ++j) {
      const int idx = (wn + j * 16 + col) * 4 + sA_sw;
      bh[j] = B8h[idx];
      bl[j] = B8l[idx];
    }
#pragma unroll
    for (int i = 0; i < 4; ++i)
#pragma unroll
      for (int j = 0; j < 4; ++j) {
        acc[i][j] = __builtin_amdgcn_mfma_f32_16x16x32_f16(ah[i], bh[j], acc[i][j], 0, 0, 0);
        acc[i][j] = __builtin_amdgcn_mfma_f32_16x16x32_f16(ah[i], bl[j], acc[i][j], 0, 0, 0);
        acc[i][j] = __builtin_amdgcn_mfma_f32_16x16x32_f16(al[i], bh[j], acc[i][j], 0, 0, 0);
      }
    __syncthreads();
  }

  const long cm = tile_m + wm + quad * 4;
  const long cn = tile_n + wn + col;
  if (CMODE == 0) {
    f16* Ch = (f16*)C + offC;
    f16* Clp = Cl + offC;
#pragma unroll
    for (int i = 0; i < 4; ++i)
#pragma unroll
      for (int r = 0; r < 4; ++r) {
        const long rowb = (cm + i * 16 + r) * (long)ldc;
#pragma unroll
        for (int j = 0; j < 4; ++j) {
          const float v = acc[i][j][r] * scale;
          const f16 hi = (f16)v;
          Ch[rowb + cn + j * 16] = hi;
          Clp[rowb + cn + j * 16] = (f16)(v - (float)hi);
        }
      }
  } else {
    float* Cp = (float*)C + offC;
#pragma unroll
    for (int i = 0; i < 4; ++i)
#pragma unroll
      for (int r = 0; r < 4; ++r) {
        const long rowb = (cm + i * 16 + r) * (long)ldc;
#pragma unroll
        for (int j = 0; j < 4; ++j)
          Cp[rowb + cn + j * 16] = acc[i][j][r] * scale;
      }
  }
}

// ===========================================================================
// 256x256 cores, phase-merged (R3): 32-MFMA clusters, halved barrier count.
// Conflict-free LDS: stage chunk c0 = ((lane&3)-((lane>>3)&3))&3 (linear
// dest), read slot (quad+((col>>1)&3))&3 — verified 0-conflict in R2.
// Counted vmcnt (oldest-first): derivations in per-phase comments.
// ===========================================================================

template <int BASE>
__device__ __forceinline__ void mfma4x4(f32x4 (&acc)[8][4],
                                        const f16x8 (&a)[4], const f16x8 (&b)[4]) {
#pragma unroll
  for (int i = 0; i < 4; ++i)
#pragma unroll
    for (int j = 0; j < 4; ++j)
      acc[BASE + i][j] =
          __builtin_amdgcn_mfma_f32_16x16x32_f16(a[i], b[j], acc[BASE + i][j], 0, 0, 0);
}

__device__ __forceinline__ void ld4(f16x8 (&d)[4], const f16* base, int off) {
#pragma unroll
  for (int k = 0; k < 4; ++k) d[k] = *(const f16x8*)(base + off + k * 512);
}

// Plain NT: C = A(MxK).B(NxK)^T, BK=64, 2 phases/K-tile, 32 MFMA each.
__device__ __forceinline__ void core_plain2(
    const f16* __restrict__ pa, const f16* __restrict__ pb,
    int K, int lda, int ldb, f16* As, f16* Bs, f32x4 (&acc)[8][4])
{
  const int tid  = threadIdx.x;
  const int wave = tid >> 6;
  const int lane = tid & 63;
  const int quad = lane >> 4;
  const int col  = lane & 15;
  const int wm = (wave >> 2) * 128;
  const int wn = (wave & 3) * 64;
  const int l_off = wave * 512 + lane * 8;
  const int r0 = wave * 16 + (lane >> 2);
  const int c0 = ((lane & 3) - ((lane >> 3) & 3)) & 3;
  const long gA  = (long)r0 * lda + c0 * 8;
  const long gA2 = gA + 128L * lda;
  const long gB  = (long)r0 * ldb + c0 * 8;
  const long gB2 = gB + 128L * ldb;
  const int sw = ((quad + ((col >> 1) & 3)) & 3) * 8;
  const int a_off = (wm + col) * 32 + sw;
  const int b_off = (wn + col) * 32 + sw;

  // prologue: tile0 kk0(A,B) then kk1(A,B)
  gl_lds16(pa + gA,       As + l_off);
  gl_lds16(pa + gA2,      As + l_off + 4096);
  gl_lds16(pb + gB,       Bs + l_off);
  gl_lds16(pb + gB2,      Bs + l_off + 4096);
  gl_lds16(pa + 32 + gA,  As + 8192 + l_off);
  gl_lds16(pa + 32 + gA2, As + 8192 + l_off + 4096);
  gl_lds16(pb + 32 + gB,  Bs + 8192 + l_off);
  gl_lds16(pb + 32 + gB2, Bs + 8192 + l_off + 4096);
  pa += 64; pb += 64;
  VMCNT4;  // kk0 A,B landed
  BAR();

  const int NT = K >> 6;
  int buf = 0;
  for (int t = 0; t < NT; ++t) {
    const f16* Ac = As + buf * 16384;
    const f16* Bc = Bs + buf * 16384;
    f16* An = As + (buf ^ 1) * 16384;
    f16* Bn = Bs + (buf ^ 1) * 16384;
    const bool last = (t == NT - 1);
    f16x8 af[4], af2[4], bf[4];

    // P1: kk0 (i0-7) | stage next kk0 | end: ensure cur kk1 landed.
    // outstanding: [Akk1_t 2][Bkk1_t 2](+[Akk0n 2][Bkk0n 2]) -> vmcnt(4)/(0)
    ld4(af,  Ac, a_off);
    ld4(af2, Ac, a_off + 2048);
    ld4(bf,  Bc, b_off);
    if (!last) {
      gl_lds16(pa + gA,  An + l_off);
      gl_lds16(pa + gA2, An + l_off + 4096);
      gl_lds16(pb + gB,  Bn + l_off);
      gl_lds16(pb + gB2, Bn + l_off + 4096);
      VMCNT4;
    } else VMCNT0;
    BAR(); LGKM0;
    __builtin_amdgcn_s_setprio(1);
    mfma4x4<0>(acc, af, bf); mfma4x4<4>(acc, af2, bf);
    __builtin_amdgcn_s_setprio(0);
    BAR();

    // P2: kk1 (i0-7) | stage next kk1 | end: ensure next kk0 landed.
    // outstanding: [Akk0n 2][Bkk0n 2][Akk1n 2][Bkk1n 2] -> vmcnt(4)
    ld4(af,  Ac, 8192 + a_off);
    ld4(af2, Ac, 8192 + a_off + 2048);
    ld4(bf,  Bc, 8192 + b_off);
    if (!last) {
      gl_lds16(pa + 32 + gA,  An + 8192 + l_off);
      gl_lds16(pa + 32 + gA2, An + 8192 + l_off + 4096);
      gl_lds16(pb + 32 + gB,  Bn + 8192 + l_off);
      gl_lds16(pb + 32 + gB2, Bn + 8192 + l_off + 4096);
      VMCNT4;
    }
    BAR(); LGKM0;
    __builtin_amdgcn_s_setprio(1);
    mfma4x4<0>(acc, af, bf); mfma4x4<4>(acc, af2, bf);
    __builtin_amdgcn_s_setprio(0);
    BAR();

    pa += 64; pb += 64; buf ^= 1;
  }
}

// Split NT: C = Ah.Bh^T + Ah.Bl^T + Al.Bh^T, BK=32, 3 phases, 32 MFMA each.
__device__ __forceinline__ void core_split3(
    const f16* __restrict__ pah, const f16* __restrict__ pal,
    const f16* __restrict__ pbh, const f16* __restrict__ pbl,
    int K, int lda, int ldb, f16* LDS, f32x4 (&acc)[8][4])
{
  const int tid  = threadIdx.x;
  const int wave = tid >> 6;
  const int lane = tid & 63;
  const int quad = lane >> 4;
  const int col  = lane & 15;
  const int wm = (wave >> 2) * 128;
  const int wn = (wave & 3) * 64;
  const int l_off = wave * 512 + lane * 8;
  const int r0 = wave * 16 + (lane >> 2);
  const int c0 = ((lane & 3) - ((lane >> 3) & 3)) & 3;
  const long gA  = (long)r0 * lda + c0 * 8;
  const long gA2 = gA + 128L * lda;
  const long gB  = (long)r0 * ldb + c0 * 8;
  const long gB2 = gB + 128L * ldb;
  const int sw = ((quad + ((col >> 1) & 3)) & 3) * 8;
  const int a_off = (wm + col) * 32 + sw;
  const int b_off = (wn + col) * 32 + sw;

  f16* Ah = LDS;
  f16* Al = LDS + 16384;
  f16* Bh = LDS + 32768;
  f16* Bl = LDS + 49152;

  // prologue order: Ah, Bh, Bl, Al
  gl_lds16(pah + gA,  Ah + l_off);
  gl_lds16(pah + gA2, Ah + l_off + 4096);
  gl_lds16(pbh + gB,  Bh + l_off);
  gl_lds16(pbh + gB2, Bh + l_off + 4096);
  gl_lds16(pbl + gB,  Bl + l_off);
  gl_lds16(pbl + gB2, Bl + l_off + 4096);
  gl_lds16(pal + gA,  Al + l_off);
  gl_lds16(pal + gA2, Al + l_off + 4096);
  pah += 32; pal += 32; pbh += 32; pbl += 32;
  VMCNT4;  // Ah,Bh landed
  BAR();

  const int NT = K >> 5;
  int buf = 0;
  for (int t = 0; t < NT; ++t) {
    const int bo = buf * 8192;
    const int bn = (buf ^ 1) * 8192;
    const bool last = (t == NT - 1);
    f16x8 ah[4], ah4[4], bh[4], bl[4], al[4], al4[4];

    // P1: ah(i0-7)xbh | stage Ah_next | end: ensure Bl_t landed.
    // outstanding: [Bl_t 2][Al_t 2](+[Ahn 2]) -> vmcnt(4)/(2)
    ld4(ah,  Ah + bo, a_off);
    ld4(ah4, Ah + bo, a_off + 2048);
    ld4(bh,  Bh + bo, b_off);
    if (!last) {
      gl_lds16(pah + gA,  Ah + bn + l_off);
      gl_lds16(pah + gA2, Ah + bn + l_off + 4096);
      VMCNT4;
    } else VMCNT2;
    BAR(); LGKM0;
    __builtin_amdgcn_s_setprio(1);
    mfma4x4<0>(acc, ah, bh); mfma4x4<4>(acc, ah4, bh);
    __builtin_amdgcn_s_setprio(0);
    BAR();

    // P2: ah x bl | stage Bh,Bl next | end: ensure Al_t landed.
    // outstanding: [Al_t 2][Ahn 2][Bhn 2][Bln 2] -> vmcnt(6)/(0)
    ld4(bl, Bl + bo, b_off);
    if (!last) {
      gl_lds16(pbh + gB,  Bh + bn + l_off);
      gl_lds16(pbh + gB2, Bh + bn + l_off + 4096);
      gl_lds16(pbl + gB,  Bl + bn + l_off);
      gl_lds16(pbl + gB2, Bl + bn + l_off + 4096);
      VMCNT6;
    } else VMCNT0;
    BAR(); LGKM0;
    __builtin_amdgcn_s_setprio(1);
    mfma4x4<0>(acc, ah, bl); mfma4x4<4>(acc, ah4, bl);
    __builtin_amdgcn_s_setprio(0);
    BAR();

    // P3: al x bh | stage Al_next | end: ensure next Ah,Bh landed.
    // outstanding: [Ahn 2][Bhn 2][Bln 2][Aln 2] -> vmcnt(4)
    ld4(al,  Al + bo, a_off);
    ld4(al4, Al + bo, a_off + 2048);
    if (!last) {
      gl_lds16(pal + gA,  Al + bn + l_off);
      gl_lds16(pal + gA2, Al + bn + l_off + 4096);
      VMCNT4;
    }
    BAR(); LGKM0;
    __builtin_amdgcn_s_setprio(1);
    mfma4x4<0>(acc, al, bh); mfma4x4<4>(acc, al4, bh);
    __builtin_amdgcn_s_setprio(0);
    BAR();

    pah += 32; pal += 32; pbh += 32; pbl += 32; buf ^= 1;
  }
}

__device__ __forceinline__ void store8_f16(f16* C, long ldc, long tm, long tn,
                                           f32x4 (&acc)[8][4], float scale) {
  const int tid = threadIdx.x, wave = tid >> 6, lane = tid & 63;
  const long cm = tm + (long)((wave >> 2) * 128 + (lane >> 4) * 4);
  const long cn = tn + (long)((wave & 3) * 64 + (lane & 15));
#pragma unroll
  for (int i = 0; i < 8; ++i)
#pragma unroll
    for (int r = 0; r < 4; ++r) {
      const long rowb = (cm + i * 16 + r) * ldc;
#pragma unroll
      for (int j = 0; j < 4; ++j)
        C[rowb + cn + j * 16] = (f16)(acc[i][j][r] * scale);
    }
}

__device__ __forceinline__ void store8_f32(float* C, long ldc, long tm, long tn,
                                           f32x4 (&acc)[8][4], float scale) {
  const int tid = threadIdx.x, wave = tid >> 6, lane = tid & 63;
  const long cm = tm + (long)((wave >> 2) * 128 + (lane >> 4) * 4);
  const long cn = tn + (long)((wave & 3) * 64 + (lane & 15));
#pragma unroll
  for (int i = 0; i < 8; ++i)
#pragma unroll
    for (int r = 0; r < 4; ++r) {
      const long rowb = (cm + i * 16 + r) * ldc;
#pragma unroll
      for (int j = 0; j < 4; ++j)
        C[rowb + cn + j * 16] = acc[i][j][r] * scale;
    }
}

__device__ __forceinline__ void store8_split(f16* Ch, f16* Cl, long ldc, long tm, long tn,
                                             f32x4 (&acc)[8][4]) {
  const int tid = threadIdx.x, wave = tid >> 6, lane = tid & 63;
  const long cm = tm + (long)((wave >> 2) * 128 + (lane >> 4) * 4);
  const long cn = tn + (long)((wave & 3) * 64 + (lane & 15));
#pragma unroll
  for (int i = 0; i < 8; ++i)
#pragma unroll
    for (int r = 0; r < 4; ++r) {
      const long rowb = (cm + i * 16 + r) * ldc;
#pragma unroll
      for (int j = 0; j < 4; ++j) {
        const float v = acc[i][j][r];
        const f16 hi = (f16)v;
        Ch[rowb + cn + j * 16] = hi;
        Cl[rowb + cn + j * 16] = (f16)(v - (float)hi);
      }
    }
}

__device__ __forceinline__ void store8_atomic(float* C, long ldc, long tm, long tn,
                                              f32x4 (&acc)[8][4]) {
  const int tid = threadIdx.x, wave = tid >> 6, lane = tid & 63;
  const long cm = tm + (long)((wave >> 2) * 128 + (lane >> 4) * 4);
  const long cn = tn + (long)((wave & 3) * 64 + (lane & 15));
#pragma unroll
  for (int i = 0; i < 8; ++i)
#pragma unroll
    for (int r = 0; r < 4; ++r) {
      const long rowb = (cm + i * 16 + r) * ldc;
#pragma unroll
      for (int j = 0; j < 4; ++j)
        atomicAdd(&C[rowb + cn + j * 16], acc[i][j][r]);
    }
}

// ---------------------------------------------------------------------------
// Polymorphic fused dispatch. Block order (split first for packing):
//   [0,nSc):  scores: Sc[z] = 32 * y_cur[s][b] (split) @ X[b]^T (split)
//   [..,+nY): y_next[slot] = X (split) @ MTy[slot]^T (split), split store
//   [..,+nVt): vT_w[hh][b] = WvTg[hh] @ Xh[b]^T
//   [..,+nPv): h2_w[hh][b] = P[hh*4+b] @ vT_r[hh][b]^T
//   [..,+nOut): out += h2_r[hl] @ WoTa(head outH0+hl)^T  (f32 atomicAdd)
// ---------------------------------------------------------------------------
__global__ __launch_bounds__(512, 2) void fused8(
    const f16* __restrict__ Xh, const f16* __restrict__ Xl,
    const f16* __restrict__ ych, const f16* __restrict__ ycl,
    float* __restrict__ Sc,
    const f16* __restrict__ MTyh, const f16* __restrict__ MTyl,
    f16* __restrict__ ynh, f16* __restrict__ ynl,
    const f16* __restrict__ WvTg, f16* __restrict__ vTw,
    const f16* __restrict__ P, const f16* __restrict__ vTr,
    f16* __restrict__ h2w,
    const f16* __restrict__ h2r, const f16* __restrict__ WoTa,
    float* __restrict__ outp, int outH0,
    int nSc, int nY, int nVt, int nPv, int nOut)
{
  __shared__ f16 LDS[65536];
  const long M1 = 1024 * 1024;
  const int bx = blockIdx.x;

  f32x4 acc[8][4];
#pragma unroll
  for (int i = 0; i < 8; ++i)
#pragma unroll
    for (int j = 0; j < 4; ++j) acc[i][j] = (f32x4){0.f, 0.f, 0.f, 0.f};

  if (bx < nSc) {
    const int z = bx >> 4, t = bx & 15;
    const int s = z >> 2, b = z & 3;
    const long tm = (long)(t & 3) * 256;
    const long tn = (long)(t >> 2) * 256;
    core_split3(ych + (long)s * 4 * M1 + (long)b * M1 + tm * 1024,
                ycl + (long)s * 4 * M1 + (long)b * M1 + tm * 1024,
                Xh + (long)b * M1 + tn * 1024,
                Xl + (long)b * M1 + tn * 1024,
                1024, 1024, 1024, LDS, acc);
    store8_f32(Sc + (long)z * M1, 1024, tm, tn, acc, 32.0f);
  } else if (bx < nSc + nY) {
    const int bx2 = bx - nSc;
    const int slot = bx2 >> 6, t = bx2 & 63;
    const long tm = (long)(t & 15) * 256;
    const long tn = (long)(t >> 4) * 256;
    core_split3(Xh + tm * 1024, Xl + tm * 1024,
                MTyh + (long)slot * M1 + tn * 1024,
                MTyl + (long)slot * M1 + tn * 1024,
                1024, 1024, 1024, LDS, acc);
    store8_split(ynh + (long)slot * 4 * M1, ynl + (long)slot * 4 * M1, 1024, tm, tn, acc);
  } else if (bx < nSc + nY + nVt) {
    const int bx2 = bx - nSc - nY;
    const int pair = bx2 >> 4, t = bx2 & 15;
    const int hh = pair >> 2, b = pair & 3;
    const long tm = (long)(t & 3) * 256;
    const long tn = (long)(t >> 2) * 256;
    core_plain2(WvTg + (long)hh * M1 + tm * 1024,
                Xh + (long)b * M1 + tn * 1024,
                1024, 1024, 1024, LDS, LDS + 32768, acc);
    store8_f16(vTw + (long)hh * 4 * M1 + (long)b * M1, 1024, tm, tn, acc, 1.0f);
  } else if (bx < nSc + nY + nVt + nPv) {
    const int bx2 = bx - nSc - nY - nVt;
    const int pair = bx2 >> 4, t = bx2 & 15;
    const int hh = pair >> 2, b = pair & 3;
    const long tm = (long)(t & 3) * 256;
    const long tn = (long)(t >> 2) * 256;
    core_plain2(P + (long)(hh * 4 + b) * M1 + tm * 1024,
                vTr + (long)hh * 4 * M1 + (long)b * M1 + tn * 1024,
                1024, 1024, 1024, LDS, LDS + 32768, acc);
    store8_f16(h2w + (long)hh * 4 * M1 + (long)b * M1, 1024, tm, tn, acc, 1.0f);
  } else {
    const int bx2 = bx - nSc - nY - nVt - nPv;
    const int hl = bx2 >> 6, t = bx2 & 63;
    const long tm = (long)(t & 15) * 256;
    const long tn = (long)(t >> 4) * 256;
    core_plain2(h2r + (long)hl * 4 * M1 + tm * 1024,
                WoTa + (long)(outH0 + hl) * 1024 + tn * 8192,
                1024, 1024, 8192, LDS, LDS + 32768, acc);
    store8_atomic(outp, 1024, tm, tn, acc);
  }
}

// Row softmax over 1024-wide fp32 rows -> fp16 P. One 256-thread block/row.
__global__ __launch_bounds__(256) void softmax_rows(const float* __restrict__ Sc,
                                                    f16* __restrict__ P) {
  const long row = blockIdx.x;
  const int tid = threadIdx.x;
  const float4 v = ((const float4*)(Sc + row * 1024))[tid];
  float m = fmaxf(fmaxf(v.x, v.y), fmaxf(v.z, v.w));
#pragma unroll
  for (int off = 32; off > 0; off >>= 1) m = fmaxf(m, __shfl_xor(m, off, 64));
  __shared__ float red[4], red2[4];
  const int wv = tid >> 6, ln = tid & 63;
  if (ln == 0) red[wv] = m;
  __syncthreads();
  m = fmaxf(fmaxf(red[0], red[1]), fmaxf(red[2], red[3]));
  const float e0 = __expf(v.x - m), e1 = __expf(v.y - m);
  const float e2 = __expf(v.z - m), e3 = __expf(v.w - m);
  float s = e0 + e1 + e2 + e3;
#pragma unroll
  for (int off = 32; off > 0; off >>= 1) s += __shfl_xor(s, off, 64);
  if (ln == 0) red2[wv] = s;
  __syncthreads();
  s = red2[0] + red2[1] + red2[2] + red2[3];
  const float inv = 1.0f / s;
  f16x4 o = {(f16)(e0 * inv), (f16)(e1 * inv), (f16)(e2 * inv), (f16)(e3 * inv)};
  *(f16x4*)(P + row * 1024 + tid * 4) = o;
}

// ---------------------------------------------------------------------------
// Upfront prep:
//   [0,4096):        X split cvt (4M)
//   [4096,12288):    WQ split cvt
//   [12288,20480):   WK split cvt
//   [20480,22528):   WV transpose -> WvTa
//   [22528,24576):   WO transpose -> WoTa (1024 x 8192, ld 8192)
//   [24576,25600):   zero d_out (4M f32) for atomic out-accumulation
// ---------------------------------------------------------------------------
__global__ __launch_bounds__(256) void prep_all(
    const float* __restrict__ X, const float* __restrict__ WQ,
    const float* __restrict__ WK, const float* __restrict__ WV,
    const float* __restrict__ WO,
    f16* __restrict__ Xh, f16* __restrict__ Xl,
    f16* __restrict__ Wqh, f16* __restrict__ Wql,
    f16* __restrict__ Wkh, f16* __restrict__ Wkl,
    f16* __restrict__ WvTa, f16* __restrict__ WoTa,
    float* __restrict__ outz)
{
  __shared__ float t[64][65];
  const int bx = blockIdx.x;
  const int tid = threadIdx.x;
  const long M1 = 1024 * 1024;

  if (bx < 20480) {
    const float* src; f16 *hi, *lo; long i;
    if (bx < 4096)       { src = X;  hi = Xh;  lo = Xl;  i = (long)bx * 1024; }
    else if (bx < 12288) { src = WQ; hi = Wqh; lo = Wql; i = (long)(bx - 4096) * 1024; }
    else                 { src = WK; hi = Wkh; lo = Wkl; i = (long)(bx - 12288) * 1024; }
    i += tid * 4;
    const float4 v = *(const float4*)(src + i);
    f16 h0 = (f16)v.x, h1 = (f16)v.y, h2 = (f16)v.z, h3 = (f16)v.w;
    f16x4 oh = {h0, h1, h2, h3};
    f16x4 ol = {(f16)(v.x - (float)h0), (f16)(v.y - (float)h1),
                (f16)(v.z - (float)h2), (f16)(v.w - (float)h3)};
    *(f16x4*)(hi + i) = oh;
    *(f16x4*)(lo + i) = ol;
  } else if (bx < 22528) {
    const int t0 = bx - 20480;
    const int head = t0 >> 8;
    const int tile = t0 & 255;
    const int r0 = (tile & 15) * 64;
    const int c0 = (tile >> 4) * 64;
    const float* in = WV + (long)head * M1;
#pragma unroll
    for (int it = 0; it < 16; ++it) {
      const int idx = it * 256 + tid;
      const int rr = idx >> 6, cc = idx & 63;
      t[rr][cc] = in[(long)(r0 + rr) * 1024 + (c0 + cc)];
    }
    __syncthreads();
#pragma unroll
    for (int it = 0; it < 16; ++it) {
      const int idx = it * 256 + tid;
      const int rr = idx >> 6, cc = idx & 63;
      WvTa[(long)head * M1 + (long)(c0 + rr) * 1024 + (r0 + cc)] = (f16)t[cc][rr];
    }
  } else if (bx < 24576) {
    const int t0 = bx - 22528;
    const int rb = t0 & 127, cb = t0 >> 7;
    const int r0 = rb * 64, c0 = cb * 64;
#pragma unroll
    for (int it = 0; it < 16; ++it) {
      const int idx = it * 256 + tid;
      const int rr = idx >> 6, cc = idx & 63;
      t[rr][cc] = WO[(long)(r0 + rr) * 1024 + (c0 + cc)];
    }
    __syncthreads();
#pragma unroll
    for (int it = 0; it < 16; ++it) {
      const int idx = it * 256 + tid;
      const int rr = idx >> 6, cc = idx & 63;
      WoTa[(long)(c0 + rr) * 8192 + (r0 + cc)] = (f16)t[cc][rr];
    }
  } else {
    const long i = ((long)(bx - 24576) * 256 + tid) * 4;
    *(float4*)(outz + i) = (float4){0.f, 0.f, 0.f, 0.f};
  }
}

// ---------------------------------------------------------------------------
// B=4, S=1024, D=1024, H=8.  scores = 32 * X M X^T, M = Wq.Wk^T.
// Double-fp16 score path. G=2 head groups, 4 iterations.
// Pipeline (pack-balanced): F(g) = scores(g)+y(g+1)+vT(g)+PV(g-1)+out(g-2).
// out accumulated atomically into pre-zeroed d_out (no partials/reduce).
// Layout (f16 M-units, 128M = 256MB total):
//  Xh0 Xl4 MTh8 MTl16 h2A24 h2B32 WoTa40 WvTa48 yAh56 yAl64 yBh72 yBl80
//  vTA88 vTB96 Sc@104(f32 8M) P@120.  Wq/Wk splits overlay yA/yB (die at MT).
// ---------------------------------------------------------------------------
extern "C" void kernel_launch(void* const* d_in, const int* in_sizes, int n_in,
                              void* d_out, int out_size, void* d_ws, size_t ws_size,
                              hipStream_t stream) {
  const float* X  = (const float*)d_in[0];
  const float* WQ = (const float*)d_in[2];
  const float* WK = (const float*)d_in[3];
  const float* WV = (const float*)d_in[4];
  const float* WO = (const float*)d_in[5];
  float* out = (float*)d_out;

  const long M1 = 1024 * 1024;
  const long MB = 1024 * 1024;
  if (ws_size < (size_t)256 * MB) return;  // PIPE confirmed running R0-R2

  f16* Xh   = (f16*)d_ws;
  f16* Xl   = Xh + 4 * M1;
  f16* MTh  = Xl + 4 * M1;
  f16* MTl  = MTh + 8 * M1;
  f16* h2A  = MTl + 8 * M1;
  f16* h2B  = h2A + 8 * M1;
  f16* WoTa = h2B + 8 * M1;
  f16* WvTa = WoTa + 8 * M1;
  f16* yAh  = WvTa + 8 * M1;
  f16* yAl  = yAh + 8 * M1;
  f16* yBh  = yAl + 8 * M1;
  f16* yBl  = yBh + 8 * M1;
  f16* vTA  = yBl + 8 * M1;
  f16* vTB  = vTA + 8 * M1;
  float* Sc = (float*)(vTB + 8 * M1);
  f16* P    = (f16*)(Sc + 8 * M1);
  f16* Wqh = yAh;  // overlays, consumed by MT
  f16* Wql = yAl;
  f16* Wkh = yBh;
  f16* Wkl = yBl;

  prep_all<<<25600, 256, 0, stream>>>(X, WQ, WK, WV, WO,
                                      Xh, Xl, Wqh, Wql, Wkh, Wkl, WvTa, WoTa, out);
  // MT[h][d2][d1] = sum_e Wk[h][d2][e] * Wq[h][d1][e]
  gemm_nt3<0><<<dim3(8, 8, 8), 256, 0, stream>>>(Wkh, Wkl, Wqh, Wql, MTh, MTl,
                                                 1024, 1024, 8,
                                                 M1, 0, M1, 0, M1, 0, 1.0f);

  // Y0: y(0)->yA (MT grp0) + vT(0)->vTA (WvT grp0)
  fused8<<<256, 512, 0, stream>>>(Xh, Xl, nullptr, nullptr, Sc,
                                  MTh, MTl, yAh, yAl,
                                  WvTa, vTA,
                                  nullptr, nullptr, nullptr,
                                  nullptr, nullptr, out, 0,
                                  0, 128, 128, 0, 0);
  // F0: scores(0) from yA + y(1)->yB (MT grp1)
  fused8<<<256, 512, 0, stream>>>(Xh, Xl, yAh, yAl, Sc,
                                  MTh + 2 * M1, MTl + 2 * M1, yBh, yBl,
                                  nullptr, nullptr,
                                  nullptr, nullptr, nullptr,
                                  nullptr, nullptr, out, 0,
                                  128, 128, 0, 0, 0);
  softmax_rows<<<8192, 256, 0, stream>>>(Sc, P);
  // F1: scores(1) yB + y(2)->yA (grp2) + vT(1)->vTB (grp1) + PV(0): vTA->h2A
  fused8<<<512, 512, 0, stream>>>(Xh, Xl, yBh, yBl, Sc,
                                  MTh + 4 * M1, MTl + 4 * M1, yAh, yAl,
                                  WvTa + 2 * M1, vTB,
                                  P, vTA, h2A,
                                  nullptr, nullptr, out, 0,
                                  128, 128, 128, 128, 0);
  softmax_rows<<<8192, 256, 0, stream>>>(Sc, P);
  // F2: scores(2) yA + y(3)->yB (grp3) + vT(2)->vTA (grp2) + PV(1): vTB->h2B
  //     + out heads 0,1 from h2A
  fused8<<<640, 512, 0, stream>>>(Xh, Xl, yAh, yAl, Sc,
                                  MTh + 6 * M1, MTl + 6 * M1, yBh, yBl,
                                  WvTa + 4 * M1, vTA,
                                  P, vTB, h2B,
                                  h2A, WoTa, out, 0,
                                  128, 128, 128, 128, 128);
  softmax_rows<<<8192, 256, 0, stream>>>(Sc, P);
  // F3: scores(3) yB + vT(3)->vTB (grp3) + PV(2): vTA->h2A + out h2,h3 (h2B)
  fused8<<<512, 512, 0, stream>>>(Xh, Xl, yBh, yBl, Sc,
                                  nullptr, nullptr, nullptr, nullptr,
                                  WvTa + 6 * M1, vTB,
                                  P, vTA, h2A,
                                  h2B, WoTa, out, 2,
                                  128, 0, 128, 128, 128);
  softmax_rows<<<8192, 256, 0, stream>>>(Sc, P);
  // T: PV(3): vTB->h2B + out h4,h5 (h2A)
  fused8<<<256, 512, 0, stream>>>(Xh, Xl, nullptr, nullptr, Sc,
                                  nullptr, nullptr, nullptr, nullptr,
                                  nullptr, nullptr,
                                  P, vTB, h2B,
                                  h2A, WoTa, out, 4,
                                  0, 0, 0, 128, 128);
  // U: out h6,h7 (h2B)
  fused8<<<128, 512, 0, stream>>>(Xh, Xl, nullptr, nullptr, Sc,
                                  nullptr, nullptr, nullptr, nullptr,
                                  nullptr, nullptr,
                                  nullptr, nullptr, nullptr,
                                  h2B, WoTa, out, 6,
                                  0, 0, 0, 0, 128);
}

// Round 4
// 947.119 us; speedup vs baseline: 1.0191x; 1.0191x over previous
//
#include <hip/hip_runtime.h>

typedef _Float16 f16;
typedef _Float16 f16x4 __attribute__((ext_vector_type(4)));
typedef _Float16 f16x8 __attribute__((ext_vector_type(8)));
typedef float    f32x4 __attribute__((ext_vector_type(4)));

#define AS1 __attribute__((address_space(1)))
#define AS3 __attribute__((address_space(3)))

__device__ __forceinline__ void gl_lds16(const void* g, void* l) {
  __builtin_amdgcn_global_load_lds((const AS1 void*)g, (AS3 void*)l, 16, 0, 0);
}

#define VMCNT0 asm volatile("s_waitcnt vmcnt(0)" ::: "memory")
#define VMCNT2 asm volatile("s_waitcnt vmcnt(2)" ::: "memory")
#define VMCNT4 asm volatile("s_waitcnt vmcnt(4)" ::: "memory")
#define VMCNT6 asm volatile("s_waitcnt vmcnt(6)" ::: "memory")
#define LGKM0  asm volatile("s_waitcnt lgkmcnt(0)" ::: "memory")
#define BAR()  __builtin_amdgcn_s_barrier()

// ===========================================================================
// 128x128 split kernel — retained ONLY for MT (= Wk.Wq^T, 512 blocks).
// ===========================================================================
template <int CMODE>
__global__ __launch_bounds__(256) void gemm_nt3(
    const f16* __restrict__ Ah, const f16* __restrict__ Al,
    const f16* __restrict__ Bh, const f16* __restrict__ Bl,
    void* __restrict__ C, f16* __restrict__ Cl,
    int K, int ldc, int ZB,
    long sA1, long sA2, long sB1, long sB2, long sC1, long sC2, float scale)
{
  __shared__ __align__(16) f16 Ash[128 * 32];
  __shared__ __align__(16) f16 Asl[128 * 32];
  __shared__ __align__(16) f16 Bsh[128 * 32];
  __shared__ __align__(16) f16 Bsl[128 * 32];

  const int tid  = threadIdx.x;
  const int wave = tid >> 6;
  const int lane = tid & 63;
  const int quad = lane >> 4;
  const int col  = lane & 15;
  const int wm = (wave & 1) * 64;
  const int wn = (wave >> 1) * 64;

  const int z  = blockIdx.z;
  const int z1 = z % ZB;
  const int z2 = z / ZB;
  const long offA = (long)z1 * sA1 + (long)z2 * sA2;
  const long offB = (long)z1 * sB1 + (long)z2 * sB2;
  const long offC = (long)z1 * sC1 + (long)z2 * sC2;

  const long tile_m = (long)blockIdx.x * 128;
  const long tile_n = (long)blockIdx.y * 128;

  const int rstage = wave * 16 + (lane >> 2);
  const int kq = ((lane & 3) - ((lane >> 3) & 3)) & 3;
  const int kstage = kq * 8;
  const int lstage = (lane & 3) * 8;
  const long aoff = offA + (tile_m + rstage) * (long)K + kstage;
  const long boff = offB + (tile_n + rstage) * (long)K + kstage;
  const f16* pah = Ah + aoff;
  const f16* pal = Al + aoff;
  const f16* pbh = Bh + boff;
  const f16* pbl = Bl + boff;
  const int lds_o = rstage * 32 + lstage;
  const long skip = 64L * K;

  const int sA_sw = (quad + ((col >> 1) & 3)) & 3;

  f32x4 acc[4][4];
#pragma unroll
  for (int i = 0; i < 4; ++i)
#pragma unroll
    for (int j = 0; j < 4; ++j) acc[i][j] = (f32x4){0.f, 0.f, 0.f, 0.f};

  for (int k0 = 0; k0 < K; k0 += 32) {
    gl_lds16(pah, &Ash[lds_o]);
    gl_lds16(pah + skip, &Ash[lds_o + 64 * 32]);
    gl_lds16(pal, &Asl[lds_o]);
    gl_lds16(pal + skip, &Asl[lds_o + 64 * 32]);
    gl_lds16(pbh, &Bsh[lds_o]);
    gl_lds16(pbh + skip, &Bsh[lds_o + 64 * 32]);
    gl_lds16(pbl, &Bsl[lds_o]);
    gl_lds16(pbl + skip, &Bsl[lds_o + 64 * 32]);
    pah += 32; pal += 32; pbh += 32; pbl += 32;
    __syncthreads();

    const f16x8* A8h = (const f16x8*)Ash;
    const f16x8* A8l = (const f16x8*)Asl;
    const f16x8* B8h = (const f16x8*)Bsh;
    const f16x8* B8l = (const f16x8*)Bsl;
    f16x8 ah[4], al[4], bh[4], bl[4];
#pragma unroll
    for (int i = 0; i < 4; ++i) {
      const int idx = (wm + i * 16 + col) * 4 + sA_sw;
      ah[i] = A8h[idx];
      al[i] = A8l[idx];
    }
#pragma unroll
    for (int j = 0; j < 4; ++j) {
      const int idx = (wn + j * 16 + col) * 4 + sA_sw;
      bh[j] = B8h[idx];
      bl[j] = B8l[idx];
    }
#pragma unroll
    for (int i = 0; i < 4; ++i)
#pragma unroll
      for (int j = 0; j < 4; ++j) {
        acc[i][j] = __builtin_amdgcn_mfma_f32_16x16x32_f16(ah[i], bh[j], acc[i][j], 0, 0, 0);
        acc[i][j] = __builtin_amdgcn_mfma_f32_16x16x32_f16(ah[i], bl[j], acc[i][j], 0, 0, 0);
        acc[i][j] = __builtin_amdgcn_mfma_f32_16x16x32_f16(al[i], bh[j], acc[i][j], 0, 0, 0);
      }
    __syncthreads();
  }

  const long cm = tile_m + wm + quad * 4;
  const long cn = tile_n + wn + col;
  if (CMODE == 0) {
    f16* Ch = (f16*)C + offC;
    f16* Clp = Cl + offC;
#pragma unroll
    for (int i = 0; i < 4; ++i)
#pragma unroll
      for (int r = 0; r < 4; ++r) {
        const long rowb = (cm + i * 16 + r) * (long)ldc;
#pragma unroll
        for (int j = 0; j < 4; ++j) {
          const float v = acc[i][j][r] * scale;
          const f16 hi = (f16)v;
          Ch[rowb + cn + j * 16] = hi;
          Clp[rowb + cn + j * 16] = (f16)(v - (float)hi);
        }
      }
  } else {
    float* Cp = (float*)C + offC;
#pragma unroll
    for (int i = 0; i < 4; ++i)
#pragma unroll
      for (int r = 0; r < 4; ++r) {
        const long rowb = (cm + i * 16 + r) * (long)ldc;
#pragma unroll
        for (int j = 0; j < 4; ++j)
          Cp[rowb + cn + j * 16] = acc[i][j][r] * scale;
      }
  }
}

// ===========================================================================
// 256x256 cores — R2-verified fine-phase schedules (R4: reverted from the
// R3 phase-merge, which was the m196 "coarse phase-split" regression:
// u 28us -> 44.6us/unit).  16-MFMA clusters, 4-8 ds_reads per phase.
// Conflict-free LDS: stage chunk c0 = ((lane&3)-((lane>>3)&3))&3 (linear
// dest), read slot (quad+((col>>1)&3))&3 — verified 0-conflict R2/R3.
// ===========================================================================

template <int BASE>
__device__ __forceinline__ void mfma4x4(f32x4 (&acc)[8][4],
                                        const f16x8 (&a)[4], const f16x8 (&b)[4]) {
#pragma unroll
  for (int i = 0; i < 4; ++i)
#pragma unroll
    for (int j = 0; j < 4; ++j)
      acc[BASE + i][j] =
          __builtin_amdgcn_mfma_f32_16x16x32_f16(a[i], b[j], acc[BASE + i][j], 0, 0, 0);
}

__device__ __forceinline__ void ld4(f16x8 (&d)[4], const f16* base, int off) {
#pragma unroll
  for (int k = 0; k < 4; ++k) d[k] = *(const f16x8*)(base + off + k * 512);
}

// Plain NT: C = A(MxK).B(NxK)^T, BK=64, 4 phases/K-tile, 16 MFMA each.
__device__ __forceinline__ void core_plain(
    const f16* __restrict__ pa, const f16* __restrict__ pb,
    int K, int lda, int ldb, f16* As, f16* Bs, f32x4 (&acc)[8][4])
{
  const int tid  = threadIdx.x;
  const int wave = tid >> 6;
  const int lane = tid & 63;
  const int quad = lane >> 4;
  const int col  = lane & 15;
  const int wm = (wave >> 2) * 128;
  const int wn = (wave & 3) * 64;
  const int l_off = wave * 512 + lane * 8;
  const int r0 = wave * 16 + (lane >> 2);
  const int c0 = ((lane & 3) - ((lane >> 3) & 3)) & 3;  // rotation by row>>1
  const long gA  = (long)r0 * lda + c0 * 8;
  const long gA2 = gA + 128L * lda;
  const long gB  = (long)r0 * ldb + c0 * 8;
  const long gB2 = gB + 128L * ldb;
  const int sw = ((quad + ((col >> 1) & 3)) & 3) * 8;
  const int a_off = (wm + col) * 32 + sw;
  const int b_off = (wn + col) * 32 + sw;

  // prologue: tile 0 units U1=A.kk0 U2=B.kk0 U3=A.kk1 U4=B.kk1
  gl_lds16(pa + gA,       As + l_off);
  gl_lds16(pa + gA2,      As + l_off + 4096);
  gl_lds16(pb + gB,       Bs + l_off);
  gl_lds16(pb + gB2,      Bs + l_off + 4096);
  gl_lds16(pa + 32 + gA,  As + 8192 + l_off);
  gl_lds16(pa + 32 + gA2, As + 8192 + l_off + 4096);
  gl_lds16(pb + 32 + gB,  Bs + 8192 + l_off);
  gl_lds16(pb + 32 + gB2, Bs + 8192 + l_off + 4096);
  pa += 64; pb += 64;
  VMCNT4;
  BAR();

  const int NT = K >> 6;
  int buf = 0;
  for (int t = 0; t < NT; ++t) {
    const f16* Ac = As + buf * 16384;
    const f16* Bc = Bs + buf * 16384;
    f16* An = As + (buf ^ 1) * 16384;
    f16* Bn = Bs + (buf ^ 1) * 16384;
    const bool last = (t == NT - 1);
    f16x8 af[4], bf[4];

    // phase 1: kk0, i0-3 | stage next U1
    ld4(af, Ac, a_off);
    ld4(bf, Bc, b_off);
    if (!last) { gl_lds16(pa + gA, An + l_off); gl_lds16(pa + gA2, An + l_off + 4096); }
    BAR(); LGKM0;
    __builtin_amdgcn_s_setprio(1); mfma4x4<0>(acc, af, bf); __builtin_amdgcn_s_setprio(0);
    BAR();

    // phase 2: kk0, i4-7 | stage next U2 | vmcnt: cur kk1 resident
    ld4(af, Ac, a_off + 2048);
    if (!last) { gl_lds16(pb + gB, Bn + l_off); gl_lds16(pb + gB2, Bn + l_off + 4096); VMCNT4; }
    else VMCNT0;
    BAR(); LGKM0;
    __builtin_amdgcn_s_setprio(1); mfma4x4<4>(acc, af, bf); __builtin_amdgcn_s_setprio(0);
    BAR();

    // phase 3: kk1, i0-3 | stage next U3
    ld4(af, Ac, 8192 + a_off);
    ld4(bf, Bc, 8192 + b_off);
    if (!last) { gl_lds16(pa + 32 + gA, An + 8192 + l_off); gl_lds16(pa + 32 + gA2, An + 8192 + l_off + 4096); }
    BAR(); LGKM0;
    __builtin_amdgcn_s_setprio(1); mfma4x4<0>(acc, af, bf); __builtin_amdgcn_s_setprio(0);
    BAR();

    // phase 4: kk1, i4-7 | stage next U4 | vmcnt: next kk0 resident
    ld4(af, Ac, 8192 + a_off + 2048);
    if (!last) { gl_lds16(pb + 32 + gB, Bn + 8192 + l_off); gl_lds16(pb + 32 + gB2, Bn + 8192 + l_off + 4096); VMCNT4; }
    BAR(); LGKM0;
    __builtin_amdgcn_s_setprio(1); mfma4x4<4>(acc, af, bf); __builtin_amdgcn_s_setprio(0);
    BAR();

    pa += 64; pb += 64; buf ^= 1;
  }
}

// Split (double-f16) NT: C = Ah.Bh^T + Ah.Bl^T + Al.Bh^T, BK=32, 6 phases.
__device__ __forceinline__ void core_split(
    const f16* __restrict__ pah, const f16* __restrict__ pal,
    const f16* __restrict__ pbh, const f16* __restrict__ pbl,
    int K, int lda, int ldb, f16* LDS, f32x4 (&acc)[8][4])
{
  const int tid  = threadIdx.x;
  const int wave = tid >> 6;
  const int lane = tid & 63;
  const int quad = lane >> 4;
  const int col  = lane & 15;
  const int wm = (wave >> 2) * 128;
  const int wn = (wave & 3) * 64;
  const int l_off = wave * 512 + lane * 8;
  const int r0 = wave * 16 + (lane >> 2);
  const int c0 = ((lane & 3) - ((lane >> 3) & 3)) & 3;  // rotation by row>>1
  const long gA  = (long)r0 * lda + c0 * 8;
  const long gA2 = gA + 128L * lda;
  const long gB  = (long)r0 * ldb + c0 * 8;
  const long gB2 = gB + 128L * ldb;
  const int sw = ((quad + ((col >> 1) & 3)) & 3) * 8;
  const int a_off = (wm + col) * 32 + sw;
  const int b_off = (wn + col) * 32 + sw;

  f16* Ah = LDS;
  f16* Al = LDS + 16384;
  f16* Bh = LDS + 32768;
  f16* Bl = LDS + 49152;

  // prologue: tile 0 units U1=Ah U2=Bh U3=Bl U4=Al
  gl_lds16(pah + gA,  Ah + l_off);
  gl_lds16(pah + gA2, Ah + l_off + 4096);
  gl_lds16(pbh + gB,  Bh + l_off);
  gl_lds16(pbh + gB2, Bh + l_off + 4096);
  gl_lds16(pbl + gB,  Bl + l_off);
  gl_lds16(pbl + gB2, Bl + l_off + 4096);
  gl_lds16(pal + gA,  Al + l_off);
  gl_lds16(pal + gA2, Al + l_off + 4096);
  pah += 32; pal += 32; pbh += 32; pbl += 32;
  VMCNT4;
  BAR();

  const int NT = K >> 5;
  int buf = 0;
  for (int t = 0; t < NT; ++t) {
    const int bo = buf * 8192;
    const int bn = (buf ^ 1) * 8192;
    const bool last = (t == NT - 1);
    f16x8 ah[4], ah4[4], bh[4], bl[4], al[4], al4[4];

    // p1: hh i0-3 | stage next Ah
    ld4(ah,  Ah + bo, a_off);
    ld4(bh,  Bh + bo, b_off);
    if (!last) { gl_lds16(pah + gA, Ah + bn + l_off); gl_lds16(pah + gA2, Ah + bn + l_off + 4096); }
    BAR(); LGKM0;
    __builtin_amdgcn_s_setprio(1); mfma4x4<0>(acc, ah, bh); __builtin_amdgcn_s_setprio(0);
    BAR();

    // p2: hh i4-7 | stage next Bh | vmcnt: cur Bl,Al resident
    ld4(ah4, Ah + bo, a_off + 2048);
    if (!last) { gl_lds16(pbh + gB, Bh + bn + l_off); gl_lds16(pbh + gB2, Bh + bn + l_off + 4096); VMCNT4; }
    else VMCNT0;
    BAR(); LGKM0;
    __builtin_amdgcn_s_setprio(1); mfma4x4<4>(acc, ah4, bh); __builtin_amdgcn_s_setprio(0);
    BAR();

    // p3: h.l i0-3 | stage next Bl
    ld4(bl, Bl + bo, b_off);
    if (!last) { gl_lds16(pbl + gB, Bl + bn + l_off); gl_lds16(pbl + gB2, Bl + bn + l_off + 4096); }
    BAR(); LGKM0;
    __builtin_amdgcn_s_setprio(1); mfma4x4<0>(acc, ah, bl); __builtin_amdgcn_s_setprio(0);
    BAR();

    // p4: h.l i4-7 | stage next Al
    ld4(al, Al + bo, a_off);
    if (!last) { gl_lds16(pal + gA, Al + bn + l_off); gl_lds16(pal + gA2, Al + bn + l_off + 4096); }
    BAR(); LGKM0;
    __builtin_amdgcn_s_setprio(1); mfma4x4<4>(acc, ah4, bl); __builtin_amdgcn_s_setprio(0);
    BAR();

    // p5: l.h i0-3
    ld4(al4, Al + bo, a_off + 2048);
    BAR(); LGKM0;
    __builtin_amdgcn_s_setprio(1); mfma4x4<0>(acc, al, bh); __builtin_amdgcn_s_setprio(0);
    BAR();

    // p6: l.h i4-7 | vmcnt: next Ah,Bh resident
    if (!last) VMCNT4;
    BAR();
    __builtin_amdgcn_s_setprio(1); mfma4x4<4>(acc, al4, bh); __builtin_amdgcn_s_setprio(0);
    BAR();

    pah += 32; pal += 32; pbh += 32; pbl += 32; buf ^= 1;
  }
}

__device__ __forceinline__ void store8_f16(f16* C, long ldc, long tm, long tn,
                                           f32x4 (&acc)[8][4], float scale) {
  const int tid = threadIdx.x, wave = tid >> 6, lane = tid & 63;
  const long cm = tm + (long)((wave >> 2) * 128 + (lane >> 4) * 4);
  const long cn = tn + (long)((wave & 3) * 64 + (lane & 15));
#pragma unroll
  for (int i = 0; i < 8; ++i)
#pragma unroll
    for (int r = 0; r < 4; ++r) {
      const long rowb = (cm + i * 16 + r) * ldc;
#pragma unroll
      for (int j = 0; j < 4; ++j)
        C[rowb + cn + j * 16] = (f16)(acc[i][j][r] * scale);
    }
}

__device__ __forceinline__ void store8_f32(float* C, long ldc, long tm, long tn,
                                           f32x4 (&acc)[8][4], float scale) {
  const int tid = threadIdx.x, wave = tid >> 6, lane = tid & 63;
  const long cm = tm + (long)((wave >> 2) * 128 + (lane >> 4) * 4);
  const long cn = tn + (long)((wave & 3) * 64 + (lane & 15));
#pragma unroll
  for (int i = 0; i < 8; ++i)
#pragma unroll
    for (int r = 0; r < 4; ++r) {
      const long rowb = (cm + i * 16 + r) * ldc;
#pragma unroll
      for (int j = 0; j < 4; ++j)
        C[rowb + cn + j * 16] = acc[i][j][r] * scale;
    }
}

__device__ __forceinline__ void store8_split(f16* Ch, f16* Cl, long ldc, long tm, long tn,
                                             f32x4 (&acc)[8][4]) {
  const int tid = threadIdx.x, wave = tid >> 6, lane = tid & 63;
  const long cm = tm + (long)((wave >> 2) * 128 + (lane >> 4) * 4);
  const long cn = tn + (long)((wave & 3) * 64 + (lane & 15));
#pragma unroll
  for (int i = 0; i < 8; ++i)
#pragma unroll
    for (int r = 0; r < 4; ++r) {
      const long rowb = (cm + i * 16 + r) * ldc;
#pragma unroll
      for (int j = 0; j < 4; ++j) {
        const float v = acc[i][j][r];
        const f16 hi = (f16)v;
        Ch[rowb + cn + j * 16] = hi;
        Cl[rowb + cn + j * 16] = (f16)(v - (float)hi);
      }
    }
}

__device__ __forceinline__ void store8_atomic(float* C, long ldc, long tm, long tn,
                                              f32x4 (&acc)[8][4]) {
  const int tid = threadIdx.x, wave = tid >> 6, lane = tid & 63;
  const long cm = tm + (long)((wave >> 2) * 128 + (lane >> 4) * 4);
  const long cn = tn + (long)((wave & 3) * 64 + (lane & 15));
#pragma unroll
  for (int i = 0; i < 8; ++i)
#pragma unroll
    for (int r = 0; r < 4; ++r) {
      const long rowb = (cm + i * 16 + r) * ldc;
#pragma unroll
      for (int j = 0; j < 4; ++j)
        atomicAdd(&C[rowb + cn + j * 16], acc[i][j][r]);
    }
}

// ---------------------------------------------------------------------------
// Polymorphic fused dispatch. Block order (split first for packing):
//   [0,nSc):  scores: Sc[z] = 32 * y_cur[s][b] (split) @ X[b]^T (split)
//   [..,+nY): y_next[slot] = X (split) @ MTy[slot]^T (split), split store
//   [..,+nVt): vT_w[hh][b] = WvTg[hh] @ Xh[b]^T
//   [..,+nPv): h2_w[hh][b] = P[hh*4+b] @ vT_r[hh][b]^T
//   [..,+nOut): out += h2_r[hl] @ WoTa(head outH0+hl)^T  (f32 atomicAdd)
// ---------------------------------------------------------------------------
__global__ __launch_bounds__(512, 2) void fused8(
    const f16* __restrict__ Xh, const f16* __restrict__ Xl,
    const f16* __restrict__ ych, const f16* __restrict__ ycl,
    float* __restrict__ Sc,
    const f16* __restrict__ MTyh, const f16* __restrict__ MTyl,
    f16* __restrict__ ynh, f16* __restrict__ ynl,
    const f16* __restrict__ WvTg, f16* __restrict__ vTw,
    const f16* __restrict__ P, const f16* __restrict__ vTr,
    f16* __restrict__ h2w,
    const f16* __restrict__ h2r, const f16* __restrict__ WoTa,
    float* __restrict__ outp, int outH0,
    int nSc, int nY, int nVt, int nPv, int nOut)
{
  __shared__ f16 LDS[65536];
  const long M1 = 1024 * 1024;
  const int bx = blockIdx.x;

  f32x4 acc[8][4];
#pragma unroll
  for (int i = 0; i < 8; ++i)
#pragma unroll
    for (int j = 0; j < 4; ++j) acc[i][j] = (f32x4){0.f, 0.f, 0.f, 0.f};

  if (bx < nSc) {
    const int z = bx >> 4, t = bx & 15;
    const int s = z >> 2, b = z & 3;
    const long tm = (long)(t & 3) * 256;
    const long tn = (long)(t >> 2) * 256;
    core_split(ych + (long)s * 4 * M1 + (long)b * M1 + tm * 1024,
               ycl + (long)s * 4 * M1 + (long)b * M1 + tm * 1024,
               Xh + (long)b * M1 + tn * 1024,
               Xl + (long)b * M1 + tn * 1024,
               1024, 1024, 1024, LDS, acc);
    store8_f32(Sc + (long)z * M1, 1024, tm, tn, acc, 32.0f);
  } else if (bx < nSc + nY) {
    const int bx2 = bx - nSc;
    const int slot = bx2 >> 6, t = bx2 & 63;
    const long tm = (long)(t & 15) * 256;
    const long tn = (long)(t >> 4) * 256;
    core_split(Xh + tm * 1024, Xl + tm * 1024,
               MTyh + (long)slot * M1 + tn * 1024,
               MTyl + (long)slot * M1 + tn * 1024,
               1024, 1024, 1024, LDS, acc);
    store8_split(ynh + (long)slot * 4 * M1, ynl + (long)slot * 4 * M1, 1024, tm, tn, acc);
  } else if (bx < nSc + nY + nVt) {
    const int bx2 = bx - nSc - nY;
    const int pair = bx2 >> 4, t = bx2 & 15;
    const int hh = pair >> 2, b = pair & 3;
    const long tm = (long)(t & 3) * 256;
    const long tn = (long)(t >> 2) * 256;
    core_plain(WvTg + (long)hh * M1 + tm * 1024,
               Xh + (long)b * M1 + tn * 1024,
               1024, 1024, 1024, LDS, LDS + 32768, acc);
    store8_f16(vTw + (long)hh * 4 * M1 + (long)b * M1, 1024, tm, tn, acc, 1.0f);
  } else if (bx < nSc + nY + nVt + nPv) {
    const int bx2 = bx - nSc - nY - nVt;
    const int pair = bx2 >> 4, t = bx2 & 15;
    const int hh = pair >> 2, b = pair & 3;
    const long tm = (long)(t & 3) * 256;
    const long tn = (long)(t >> 2) * 256;
    core_plain(P + (long)(hh * 4 + b) * M1 + tm * 1024,
               vTr + (long)hh * 4 * M1 + (long)b * M1 + tn * 1024,
               1024, 1024, 1024, LDS, LDS + 32768, acc);
    store8_f16(h2w + (long)hh * 4 * M1 + (long)b * M1, 1024, tm, tn, acc, 1.0f);
  } else {
    const int bx2 = bx - nSc - nY - nVt - nPv;
    const int hl = bx2 >> 6, t = bx2 & 63;
    const long tm = (long)(t & 15) * 256;
    const long tn = (long)(t >> 4) * 256;
    core_plain(h2r + (long)hl * 4 * M1 + tm * 1024,
               WoTa + (long)(outH0 + hl) * 1024 + tn * 8192,
               1024, 1024, 8192, LDS, LDS + 32768, acc);
    store8_atomic(outp, 1024, tm, tn, acc);
  }
}

// Row softmax over 1024-wide fp32 rows -> fp16 P. One 256-thread block/row.
__global__ __launch_bounds__(256) void softmax_rows(const float* __restrict__ Sc,
                                                    f16* __restrict__ P) {
  const long row = blockIdx.x;
  const int tid = threadIdx.x;
  const float4 v = ((const float4*)(Sc + row * 1024))[tid];
  float m = fmaxf(fmaxf(v.x, v.y), fmaxf(v.z, v.w));
#pragma unroll
  for (int off = 32; off > 0; off >>= 1) m = fmaxf(m, __shfl_xor(m, off, 64));
  __shared__ float red[4], red2[4];
  const int wv = tid >> 6, ln = tid & 63;
  if (ln == 0) red[wv] = m;
  __syncthreads();
  m = fmaxf(fmaxf(red[0], red[1]), fmaxf(red[2], red[3]));
  const float e0 = __expf(v.x - m), e1 = __expf(v.y - m);
  const float e2 = __expf(v.z - m), e3 = __expf(v.w - m);
  float s = e0 + e1 + e2 + e3;
#pragma unroll
  for (int off = 32; off > 0; off >>= 1) s += __shfl_xor(s, off, 64);
  if (ln == 0) red2[wv] = s;
  __syncthreads();
  s = red2[0] + red2[1] + red2[2] + red2[3];
  const float inv = 1.0f / s;
  f16x4 o = {(f16)(e0 * inv), (f16)(e1 * inv), (f16)(e2 * inv), (f16)(e3 * inv)};
  *(f16x4*)(P + row * 1024 + tid * 4) = o;
}

// ---------------------------------------------------------------------------
// Upfront prep:
//   [0,4096):        X split cvt (4M)
//   [4096,12288):    WQ split cvt
//   [12288,20480):   WK split cvt
//   [20480,22528):   WV transpose -> WvTa
//   [22528,24576):   WO transpose -> WoTa (1024 x 8192, ld 8192)
//   [24576,25600):   zero d_out (4M f32) for atomic out-accumulation
// ---------------------------------------------------------------------------
__global__ __launch_bounds__(256) void prep_all(
    const float* __restrict__ X, const float* __restrict__ WQ,
    const float* __restrict__ WK, const float* __restrict__ WV,
    const float* __restrict__ WO,
    f16* __restrict__ Xh, f16* __restrict__ Xl,
    f16* __restrict__ Wqh, f16* __restrict__ Wql,
    f16* __restrict__ Wkh, f16* __restrict__ Wkl,
    f16* __restrict__ WvTa, f16* __restrict__ WoTa,
    float* __restrict__ outz)
{
  __shared__ float t[64][65];
  const int bx = blockIdx.x;
  const int tid = threadIdx.x;
  const long M1 = 1024 * 1024;

  if (bx < 20480) {
    const float* src; f16 *hi, *lo; long i;
    if (bx < 4096)       { src = X;  hi = Xh;  lo = Xl;  i = (long)bx * 1024; }
    else if (bx < 12288) { src = WQ; hi = Wqh; lo = Wql; i = (long)(bx - 4096) * 1024; }
    else                 { src = WK; hi = Wkh; lo = Wkl; i = (long)(bx - 12288) * 1024; }
    i += tid * 4;
    const float4 v = *(const float4*)(src + i);
    f16 h0 = (f16)v.x, h1 = (f16)v.y, h2 = (f16)v.z, h3 = (f16)v.w;
    f16x4 oh = {h0, h1, h2, h3};
    f16x4 ol = {(f16)(v.x - (float)h0), (f16)(v.y - (float)h1),
                (f16)(v.z - (float)h2), (f16)(v.w - (float)h3)};
    *(f16x4*)(hi + i) = oh;
    *(f16x4*)(lo + i) = ol;
  } else if (bx < 22528) {
    const int t0 = bx - 20480;
    const int head = t0 >> 8;
    const int tile = t0 & 255;
    const int r0 = (tile & 15) * 64;
    const int c0 = (tile >> 4) * 64;
    const float* in = WV + (long)head * M1;
#pragma unroll
    for (int it = 0; it < 16; ++it) {
      const int idx = it * 256 + tid;
      const int rr = idx >> 6, cc = idx & 63;
      t[rr][cc] = in[(long)(r0 + rr) * 1024 + (c0 + cc)];
    }
    __syncthreads();
#pragma unroll
    for (int it = 0; it < 16; ++it) {
      const int idx = it * 256 + tid;
      const int rr = idx >> 6, cc = idx & 63;
      WvTa[(long)head * M1 + (long)(c0 + rr) * 1024 + (r0 + cc)] = (f16)t[cc][rr];
    }
  } else if (bx < 24576) {
    const int t0 = bx - 22528;
    const int rb = t0 & 127, cb = t0 >> 7;
    const int r0 = rb * 64, c0 = cb * 64;
#pragma unroll
    for (int it = 0; it < 16; ++it) {
      const int idx = it * 256 + tid;
      const int rr = idx >> 6, cc = idx & 63;
      t[rr][cc] = WO[(long)(r0 + rr) * 1024 + (c0 + cc)];
    }
    __syncthreads();
#pragma unroll
    for (int it = 0; it < 16; ++it) {
      const int idx = it * 256 + tid;
      const int rr = idx >> 6, cc = idx & 63;
      WoTa[(long)(c0 + rr) * 8192 + (r0 + cc)] = (f16)t[cc][rr];
    }
  } else {
    const long i = ((long)(bx - 24576) * 256 + tid) * 4;
    *(float4*)(outz + i) = (float4){0.f, 0.f, 0.f, 0.f};
  }
}

// ---------------------------------------------------------------------------
// B=4, S=1024, D=1024, H=8.  scores = 32 * X M X^T, M = Wq.Wk^T.
// Double-fp16 score path. G=2 head groups, 4 iterations.
// Pipeline (pack-balanced): F(g) = scores(g)+y(g+1)+vT(g)+PV(g-1)+out(g-2).
// out accumulated atomically into pre-zeroed d_out (no partials/reduce).
// Layout (f16 M-units, 128M = 256MB total):
//  Xh0 Xl4 MTh8 MTl16 h2A24 h2B32 WoTa40 WvTa48 yAh56 yAl64 yBh72 yBl80
//  vTA88 vTB96 Sc@104(f32 8M) P@120.  Wq/Wk splits overlay yA/yB (die at MT).
// ---------------------------------------------------------------------------
extern "C" void kernel_launch(void* const* d_in, const int* in_sizes, int n_in,
                              void* d_out, int out_size, void* d_ws, size_t ws_size,
                              hipStream_t stream) {
  const float* X  = (const float*)d_in[0];
  const float* WQ = (const float*)d_in[2];
  const float* WK = (const float*)d_in[3];
  const float* WV = (const float*)d_in[4];
  const float* WO = (const float*)d_in[5];
  float* out = (float*)d_out;

  const long M1 = 1024 * 1024;
  const long MB = 1024 * 1024;
  if (ws_size < (size_t)256 * MB) return;  // PIPE confirmed running R0-R3

  f16* Xh   = (f16*)d_ws;
  f16* Xl   = Xh + 4 * M1;
  f16* MTh  = Xl + 4 * M1;
  f16* MTl  = MTh + 8 * M1;
  f16* h2A  = MTl + 8 * M1;
  f16* h2B  = h2A + 8 * M1;
  f16* WoTa = h2B + 8 * M1;
  f16* WvTa = WoTa + 8 * M1;
  f16* yAh  = WvTa + 8 * M1;
  f16* yAl  = yAh + 8 * M1;
  f16* yBh  = yAl + 8 * M1;
  f16* yBl  = yBh + 8 * M1;
  f16* vTA  = yBl + 8 * M1;
  f16* vTB  = vTA + 8 * M1;
  float* Sc = (float*)(vTB + 8 * M1);
  f16* P    = (f16*)(Sc + 8 * M1);
  f16* Wqh = yAh;  // overlays, consumed by MT
  f16* Wql = yAl;
  f16* Wkh = yBh;
  f16* Wkl = yBl;

  prep_all<<<25600, 256, 0, stream>>>(X, WQ, WK, WV, WO,
                                      Xh, Xl, Wqh, Wql, Wkh, Wkl, WvTa, WoTa, out);
  // MT[h][d2][d1] = sum_e Wk[h][d2][e] * Wq[h][d1][e]
  gemm_nt3<0><<<dim3(8, 8, 8), 256, 0, stream>>>(Wkh, Wkl, Wqh, Wql, MTh, MTl,
                                                 1024, 1024, 8,
                                                 M1, 0, M1, 0, M1, 0, 1.0f);

  // Y0: y(0)->yA (MT grp0) + vT(0)->vTA (WvT grp0)
  fused8<<<256, 512, 0, stream>>>(Xh, Xl, nullptr, nullptr, Sc,
                                  MTh, MTl, yAh, yAl,
                                  WvTa, vTA,
                                  nullptr, nullptr, nullptr,
                                  nullptr, nullptr, out, 0,
                                  0, 128, 128, 0, 0);
  // F0: scores(0) from yA + y(1)->yB (MT grp1)
  fused8<<<256, 512, 0, stream>>>(Xh, Xl, yAh, yAl, Sc,
                                  MTh + 2 * M1, MTl + 2 * M1, yBh, yBl,
                                  nullptr, nullptr,
                                  nullptr, nullptr, nullptr,
                                  nullptr, nullptr, out, 0,
                                  128, 128, 0, 0, 0);
  softmax_rows<<<8192, 256, 0, stream>>>(Sc, P);
  // F1: scores(1) yB + y(2)->yA (grp2) + vT(1)->vTB (grp1) + PV(0): vTA->h2A
  fused8<<<512, 512, 0, stream>>>(Xh, Xl, yBh, yBl, Sc,
                                  MTh + 4 * M1, MTl + 4 * M1, yAh, yAl,
                                  WvTa + 2 * M1, vTB,
                                  P, vTA, h2A,
                                  nullptr, nullptr, out, 0,
                                  128, 128, 128, 128, 0);
  softmax_rows<<<8192, 256, 0, stream>>>(Sc, P);
  // F2: scores(2) yA + y(3)->yB (grp3) + vT(2)->vTA (grp2) + PV(1): vTB->h2B
  //     + out heads 0,1 from h2A
  fused8<<<640, 512, 0, stream>>>(Xh, Xl, yAh, yAl, Sc,
                                  MTh + 6 * M1, MTl + 6 * M1, yBh, yBl,
                                  WvTa + 4 * M1, vTA,
                                  P, vTB, h2B,
                                  h2A, WoTa, out, 0,
                                  128, 128, 128, 128, 128);
  softmax_rows<<<8192, 256, 0, stream>>>(Sc, P);
  // F3: scores(3) yB + vT(3)->vTB (grp3) + PV(2): vTA->h2A + out h2,h3 (h2B)
  fused8<<<512, 512, 0, stream>>>(Xh, Xl, yBh, yBl, Sc,
                                  nullptr, nullptr, nullptr, nullptr,
                                  WvTa + 6 * M1, vTB,
                                  P, vTA, h2A,
                                  h2B, WoTa, out, 2,
                                  128, 0, 128, 128, 128);
  softmax_rows<<<8192, 256, 0, stream>>>(Sc, P);
  // T: PV(3): vTB->h2B + out h4,h5 (h2A)
  fused8<<<256, 512, 0, stream>>>(Xh, Xl, nullptr, nullptr, Sc,
                                  nullptr, nullptr, nullptr, nullptr,
                                  nullptr, nullptr,
                                  P, vTB, h2B,
                                  h2A, WoTa, out, 4,
                                  0, 0, 0, 128, 128);
  // U: out h6,h7 (h2B)
  fused8<<<128, 512, 0, stream>>>(Xh, Xl, nullptr, nullptr, Sc,
                                  nullptr, nullptr, nullptr, nullptr,
                                  nullptr, nullptr,
                                  nullptr, nullptr, nullptr,
                                  h2B, WoTa, out, 6,
                                  0, 0, 0, 0, 128);
}